// Round 9
// baseline (418.381 us; speedup 1.0000x reference)
//
#include <hip/hip_runtime.h>

#define B_   32
#define C_   16
#define H_   128
#define W_   128
#define HW_  (H_ * W_)
#define NF_  4
#define HID_ 128
#define FIN_ (C_ * NF_)   // 64
#define NPIX (B_ * HW_)   // 524288
#define OB_  16           // o-block width: one s_load_dwordx16 feeds 32 FMAs

// W1 [128][64] -> W1t [64][128]; W2 [16][128] -> W2t [128][16].
// Contiguous wave-uniform slices -> s_load into SGPRs (zero VGPR cost).
__global__ __launch_bounds__(256) void w_transpose(
    const float* __restrict__ W1, const float* __restrict__ W2,
    float* __restrict__ W1t, float* __restrict__ W2t)
{
    int t = blockIdx.x * blockDim.x + threadIdx.x;
    if (t < HID_ * FIN_) {
        int o = t >> 6;          // 0..127
        int k = t & (FIN_ - 1);  // 0..63
        W1t[k * HID_ + o] = W1[t];
    }
    if (t < C_ * HID_) {
        int j = t >> 7;          // 0..15
        int o = t & (HID_ - 1);  // 0..127
        W2t[o * C_ + j] = W2[t];
    }
}

// Two horizontally-adjacent pixels per thread: the weight sweep (40 KB of
// s_loads, K$-missing to L2 at ~200 cyc) is amortized over 2x FMA work, and
// the conv shares 12-of-18 neighbor loads. Per k: s_load_dwordx16 + 32 FMAs
// (64 cyc issue) with ~4 loads in flight -> latency covered.
__global__ __launch_bounds__(256) void ca_step(
    const float* __restrict__ x,
    const float* __restrict__ rmask,
    const float* __restrict__ filt,
    const float* __restrict__ W1t,   // [64][128]
    const float* __restrict__ b1,
    const float* __restrict__ W2t,   // [128][16]
    const float* __restrict__ b2,
    float* __restrict__ out,
    float* __restrict__ alpha_new,
    float* __restrict__ pre_life)
{
    int t2 = blockIdx.x * blockDim.x + threadIdx.x;   // 0 .. NPIX/2-1
    if (t2 >= NPIX / 2) return;
    int b   = t2 >> 13;            // / (HW_/2)
    int rem = t2 & (HW_ / 2 - 1);
    int r   = rem >> 6;
    int c   = (rem & 63) << 1;     // even column; pair is (c, c+1)

    int rm = (r - 1) & (H_ - 1), rp = (r + 1) & (H_ - 1);
    int cm = (c - 1) & (W_ - 1), cp = c + 1, cp2 = (c + 2) & (W_ - 1);
    int rowo[3] = { rm * W_, r * W_, rp * W_ };
    int colo[4] = { cm, c, cp, cp2 };

    const float* xb = x + (size_t)b * C_ * HW_;

    float y[2][FIN_];
    float premax0 = -1e30f, presum0 = 0.f, premax1 = -1e30f, presum1 = 0.f;

    #pragma unroll
    for (int ch = 0; ch < C_; ++ch) {
        const float* xc = xb + ch * HW_;
        float n[3][4];
        #pragma unroll
        for (int rr = 0; rr < 3; ++rr)
            #pragma unroll
            for (int cc = 0; cc < 4; ++cc)
                n[rr][cc] = xc[rowo[rr] + colo[cc]];
        #pragma unroll
        for (int f = 0; f < NF_; ++f) {
            float a0 = 0.f, a1 = 0.f;
            #pragma unroll
            for (int rr = 0; rr < 3; ++rr) {
                #pragma unroll
                for (int cc = 0; cc < 3; ++cc) {
                    float w = filt[f * 9 + rr * 3 + cc];
                    a0 = fmaf(w, n[rr][cc], a0);
                    a1 = fmaf(w, n[rr][cc + 1], a1);
                }
            }
            y[0][ch * NF_ + f] = a0;
            y[1][ch * NF_ + f] = a1;
        }
        if (ch == 3) {
            #pragma unroll
            for (int rr = 0; rr < 3; ++rr) {
                premax0 = fmaxf(premax0, fmaxf(fmaxf(n[rr][0], n[rr][1]), n[rr][2]));
                premax1 = fmaxf(premax1, fmaxf(fmaxf(n[rr][1], n[rr][2]), n[rr][3]));
                presum0 += n[rr][0] + n[rr][1] + n[rr][2];
                presum1 += n[rr][1] + n[rr][2] + n[rr][3];
            }
        }
    }
    float pre0 = (premax0 > 0.1f && (presum0 * (1.0f / 9.0f)) < 0.2f) ? 1.f : 0.f;
    float pre1 = (premax1 > 0.1f && (presum1 * (1.0f / 9.0f)) < 0.2f) ? 1.f : 0.f;

    // MLP for both pixels. All inner loops fully unrolled (static indices).
    float acc[2][C_];
    #pragma unroll
    for (int j = 0; j < C_; ++j) { acc[0][j] = b2[j]; acc[1][j] = b2[j]; }

    #pragma unroll 1
    for (int ob = 0; ob < HID_ / OB_; ++ob) {   // 8 iterations
        const float* b1p = b1 + ob * OB_;
        float h0[OB_], h1[OB_];
        #pragma unroll
        for (int i = 0; i < OB_; ++i) { h0[i] = b1p[i]; h1[i] = b1p[i]; }

        const float* w1b = W1t + ob * OB_;
        #pragma unroll
        for (int k = 0; k < FIN_; ++k) {
            const float* wr = w1b + k * HID_;   // 16 contiguous uniform floats
            float y0 = y[0][k], y1 = y[1][k];
            #pragma unroll
            for (int i = 0; i < OB_; ++i) {
                float w = wr[i];
                h0[i] = fmaf(w, y0, h0[i]);
                h1[i] = fmaf(w, y1, h1[i]);
            }
        }

        const float* w2b = W2t + (ob * OB_) * C_;
        #pragma unroll
        for (int i = 0; i < OB_; ++i) {
            float t0 = h0[i]; t0 = (t0 >= 0.f) ? t0 : 0.01f * t0;
            float t1 = h1[i]; t1 = (t1 >= 0.f) ? t1 : 0.01f * t1;
            #pragma unroll
            for (int j = 0; j < C_; ++j) {
                float w = w2b[i * C_ + j];
                acc[0][j] = fmaf(w, t0, acc[0][j]);
                acc[1][j] = fmaf(w, t1, acc[1][j]);
            }
        }
    }

    int base = b * HW_ + r * W_ + c;
    float2 rmk = *(const float2*)(rmask + base);
    float um0 = (rmk.x <= 0.5f) ? 1.f : 0.f;
    float um1 = (rmk.y <= 0.5f) ? 1.f : 0.f;

    float an0 = 0.f, an1 = 0.f;
    #pragma unroll
    for (int ch = 0; ch < C_; ++ch) {
        const float* xc = xb + ch * HW_ + r * W_ + c;
        float2 xv = *(const float2*)xc;
        float2 xn;
        xn.x = xv.x + acc[0][ch] * um0;
        xn.y = xv.y + acc[1][ch] * um1;
        *(float2*)(out + (size_t)b * C_ * HW_ + ch * HW_ + r * W_ + c) = xn;
        if (ch == 3) { an0 = xn.x; an1 = xn.y; }
    }
    *(float2*)(alpha_new + base) = make_float2(an0, an1);
    *(float2*)(pre_life + base) = make_float2(pre0, pre1);
}

// Kernel B: post_life from new alpha plane; zero channels where !(pre & post).
__global__ __launch_bounds__(256) void ca_mask(
    const float* __restrict__ alpha_new,
    const float* __restrict__ pre_life,
    float* __restrict__ out)
{
    int tid = blockIdx.x * blockDim.x + threadIdx.x;
    if (tid >= NPIX) return;
    int b   = tid >> 14;
    int pix = tid & (HW_ - 1);
    int r   = pix >> 7;
    int c   = pix & (W_ - 1);

    int rm = (r - 1) & (H_ - 1), rp = (r + 1) & (H_ - 1);
    int cm = (c - 1) & (W_ - 1), cp = (c + 1) & (W_ - 1);
    int off[9] = { rm * W_ + cm, rm * W_ + c, rm * W_ + cp,
                   r  * W_ + cm, r  * W_ + c, r  * W_ + cp,
                   rp * W_ + cm, rp * W_ + c, rp * W_ + cp };

    const float* ab = alpha_new + (size_t)b * HW_;
    float mx = -1e30f, sm = 0.f;
    #pragma unroll
    for (int t = 0; t < 9; ++t) {
        float v = ab[off[t]];
        mx = fmaxf(mx, v);
        sm += v;
    }
    bool post = (mx > 0.1f) && ((sm * (1.0f / 9.0f)) < 0.2f);
    bool life = post && (pre_life[tid] > 0.5f);
    if (!life) {
        float* ob = out + (size_t)b * C_ * HW_ + pix;
        #pragma unroll
        for (int ch = 0; ch < C_; ++ch) ob[ch * HW_] = 0.f;
    }
}

extern "C" void kernel_launch(void* const* d_in, const int* in_sizes, int n_in,
                              void* d_out, int out_size, void* d_ws, size_t ws_size,
                              hipStream_t stream)
{
    const float* x     = (const float*)d_in[0];
    const float* rmask = (const float*)d_in[1];
    const float* filt  = (const float*)d_in[2];
    const float* W1    = (const float*)d_in[3];
    const float* b1    = (const float*)d_in[4];
    const float* W2    = (const float*)d_in[5];
    const float* b2    = (const float*)d_in[6];
    float* out = (float*)d_out;

    float* alpha_new = (float*)d_ws;           // NPIX floats
    float* pre_life  = alpha_new + NPIX;       // NPIX floats
    float* W1t       = pre_life + NPIX;        // 8192 floats
    float* W2t       = W1t + HID_ * FIN_;      // 2048 floats

    w_transpose<<<dim3(32), dim3(256), 0, stream>>>(W1, W2, W1t, W2t);
    ca_step<<<dim3(NPIX / 2 / 256), dim3(256), 0, stream>>>(
        x, rmask, filt, W1t, b1, W2t, b2, out, alpha_new, pre_life);
    ca_mask<<<dim3(NPIX / 256), dim3(256), 0, stream>>>(alpha_new, pre_life, out);
}

// Round 10
// 109.716 us; speedup vs baseline: 3.8133x; 3.8133x over previous
//
#include <hip/hip_runtime.h>

#define B_   32
#define C_   16
#define H_   128
#define W_   128
#define HW_  (H_ * W_)
#define HID_ 128
#define FIN_ 64
#define NPIX (B_ * HW_)

typedef float    f32x4 __attribute__((ext_vector_type(4)));
typedef _Float16 f16x8 __attribute__((ext_vector_type(8)));

#define MFMA16(A, Bv, Cv) __builtin_amdgcn_mfma_f32_16x16x32_f16((A), (Bv), (Cv), 0, 0, 0)

// Slot->k convention (shared by ALL fragments; permutation-invariant as long
// as A and B use the same map):  k = 32*kc + 16*(j>>2) + 4*(lane>>4) + (j&3)
//
// w1p: 32 frags [(nt*2+kc)*2+s][lane][j], s=0 hi / s=1 lo; o = nt*16+(lane&15)
// w2p:  8 frags [kc2*2+s][lane][j];                       ch = lane&15
__global__ __launch_bounds__(256) void w_pack(
    const float* __restrict__ W1, const float* __restrict__ W2,
    _Float16* __restrict__ w1p, _Float16* __restrict__ w2p)
{
    int t = blockIdx.x * 256 + threadIdx.x;
    if (t < 32 * 512) {
        int frag = t >> 9, rem = t & 511, l = rem >> 3, j = rem & 7;
        int nt = frag >> 2, kc = (frag >> 1) & 1, s = frag & 1;
        int o = nt * 16 + (l & 15);
        int k = kc * 32 + 16 * (j >> 2) + 4 * (l >> 4) + (j & 3);
        float v = W1[o * FIN_ + k];
        _Float16 hi = (_Float16)v;
        _Float16 lo = (_Float16)(v - (float)hi);
        w1p[t] = s ? lo : hi;
    } else if (t < 32 * 512 + 8 * 512) {
        int u = t - 32 * 512;
        int frag = u >> 9, rem = u & 511, l = rem >> 3, j = rem & 7;
        int kc2 = frag >> 1, s = frag & 1;
        int ch = l & 15;
        int o = kc2 * 32 + 16 * (j >> 2) + 4 * (l >> 4) + (j & 3);
        float v = W2[ch * HID_ + o];
        _Float16 hi = (_Float16)v;
        _Float16 lo = (_Float16)(v - (float)hi);
        w2p[u] = s ? lo : hi;
    }
}

// ca_step: per 16-px tile, one wave does conv (4 ch/lane -> y frags in-reg),
// GEMM1 h = W1*y (D[o][px]), leaky+split in-lane, GEMM2 dx = W2*h'
// (GEMM1 accs ARE GEMM2 B-frags: nt = 2*kc2+s), masked update + stores.
__global__ __launch_bounds__(256) void ca_step(
    const float* __restrict__ x,
    const float* __restrict__ rmask,
    const float* __restrict__ filt,
    const _Float16* __restrict__ w1p,
    const float* __restrict__ b1,
    const _Float16* __restrict__ w2p,
    const float* __restrict__ b2,
    float* __restrict__ out,
    float* __restrict__ alpha_new,
    float* __restrict__ pre_life)
{
    __shared__ uint4 sW1[32 * 64];   // 32 KB: w1p frags
    __shared__ uint4 sW2[8 * 64];    //  8 KB: w2p frags

    {
        const uint4* s1 = (const uint4*)w1p;
        for (int i = threadIdx.x; i < 32 * 64; i += 256) sW1[i] = s1[i];
        const uint4* s2 = (const uint4*)w2p;
        for (int i = threadIdx.x; i < 8 * 64; i += 256) sW2[i] = s2[i];
    }
    __syncthreads();

    int lane = threadIdx.x & 63, wv = threadIdx.x >> 6;
    int g = lane >> 4, li = lane & 15;
    const f16x8* w1f = (const f16x8*)sW1;
    const f16x8* w2f = (const f16x8*)sW2;

    #pragma unroll 1
    for (int pt = 0; pt < 4; ++pt) {
        int tix = blockIdx.x * 16 + wv * 4 + pt;   // 16-px tile index
        int pxg = tix * 16 + li;                   // this lane's pixel
        int b = pxg >> 14, pix = pxg & (HW_ - 1);
        int rr = pix >> 7, cc = pix & (W_ - 1);
        int rm = (rr - 1) & (H_ - 1), rp = (rr + 1) & (H_ - 1);
        int cm = (cc - 1) & (W_ - 1), cp = (cc + 1) & (W_ - 1);
        int ro[3] = { rm * W_, rr * W_, rp * W_ };
        int co[3] = { cm, cc, cp };
        const float* xb = x + (size_t)b * C_ * HW_;

        // conv: this lane covers channels {g, g+4, g+8, g+12} of pixel pxg.
        // q = kc*2+s -> ch = 8*kc + 4*s + g; frag elem j: f = j&3.
        f32x4 yv[4];
        float pmax = -1e30f, psum = 0.f;
        #pragma unroll
        for (int q = 0; q < 4; ++q) {
            int ch = g + 4 * (q & 1) + 8 * (q >> 1);
            const float* xc = xb + ch * HW_;
            float n[9];
            #pragma unroll
            for (int u = 0; u < 9; ++u) n[u] = xc[ro[u / 3] + co[u % 3]];
            #pragma unroll
            for (int f = 0; f < 4; ++f) {
                float a = 0.f;
                #pragma unroll
                for (int u = 0; u < 9; ++u) a = fmaf(filt[f * 9 + u], n[u], a);
                yv[q][f] = a;
            }
            if (q == 0 && g == 3) {   // ch == 3: alpha neighborhood
                float mx = n[0], sm = 0.f;
                #pragma unroll
                for (int u = 0; u < 9; ++u) { mx = fmaxf(mx, n[u]); sm += n[u]; }
                pmax = mx; psum = sm;
            }
        }
        if (g == 3) {
            float pre = (pmax > 0.1f && psum * (1.f / 9.f) < 0.2f) ? 1.f : 0.f;
            pre_life[pxg] = pre;
        }

        // split y -> hi/lo B-frags per kc
        f16x8 yfh[2], yfl[2];
        #pragma unroll
        for (int q = 0; q < 4; ++q) {
            int kc = q >> 1, s = q & 1;
            #pragma unroll
            for (int f = 0; f < 4; ++f) {
                float v = yv[q][f];
                _Float16 hi = (_Float16)v;
                _Float16 lo = (_Float16)(v - (float)hi);
                yfh[kc][s * 4 + f] = hi;
                yfl[kc][s * 4 + f] = lo;
            }
        }

        // fused GEMM1 -> leaky/split -> GEMM2, nt-pair per kc2
        f32x4 acc2 = { 0.f, 0.f, 0.f, 0.f };
        #pragma unroll
        for (int kc2 = 0; kc2 < 4; ++kc2) {
            f16x8 Hh, Hl;
            #pragma unroll
            for (int u = 0; u < 2; ++u) {
                int nt = kc2 * 2 + u;
                f32x4 a1 = { 0.f, 0.f, 0.f, 0.f };
                #pragma unroll
                for (int kc = 0; kc < 2; ++kc) {
                    int fb = (nt * 2 + kc) * 2;
                    f16x8 wh = w1f[(fb + 0) * 64 + lane];
                    f16x8 wl = w1f[(fb + 1) * 64 + lane];
                    a1 = MFMA16(wh, yfh[kc], a1);
                    a1 = MFMA16(wh, yfl[kc], a1);
                    a1 = MFMA16(wl, yfh[kc], a1);
                }
                // bias + leaky + split; lane holds h[o=nt*16+4g+t][px=li]
                #pragma unroll
                for (int t = 0; t < 4; ++t) {
                    float hv = a1[t] + b1[nt * 16 + 4 * g + t];
                    float hpv = fmaxf(hv, 0.01f * hv);
                    _Float16 hi = (_Float16)hpv;
                    _Float16 lo = (_Float16)(hpv - (float)hi);
                    Hh[u * 4 + t] = hi;
                    Hl[u * 4 + t] = lo;
                }
            }
            f16x8 w2h = w2f[(kc2 * 2 + 0) * 64 + lane];
            f16x8 w2l = w2f[(kc2 * 2 + 1) * 64 + lane];
            acc2 = MFMA16(w2h, Hh, acc2);
            acc2 = MFMA16(w2h, Hl, acc2);
            acc2 = MFMA16(w2l, Hh, acc2);
        }

        // epilogue: lane holds dx[ch=4g+t][px=li]
        float um = (rmask[pxg] <= 0.5f) ? 1.f : 0.f;
        float aval = 0.f;
        #pragma unroll
        for (int t = 0; t < 4; ++t) {
            int ch = 4 * g + t;
            float xv = xb[ch * HW_ + pix];
            float ov = xv + (acc2[t] + b2[ch]) * um;
            out[(size_t)b * C_ * HW_ + ch * HW_ + pix] = ov;
            if (t == 3) aval = ov;
        }
        if (g == 0) alpha_new[pxg] = aval;   // g==0,t==3 -> ch 3
    }
}

// Kernel B: post_life from new alpha plane; zero channels where !(pre & post).
__global__ __launch_bounds__(256) void ca_mask(
    const float* __restrict__ alpha_new,
    const float* __restrict__ pre_life,
    float* __restrict__ out)
{
    int tid = blockIdx.x * blockDim.x + threadIdx.x;
    if (tid >= NPIX) return;
    int b   = tid >> 14;
    int pix = tid & (HW_ - 1);
    int r   = pix >> 7;
    int c   = pix & (W_ - 1);

    int rm = (r - 1) & (H_ - 1), rp = (r + 1) & (H_ - 1);
    int cm = (c - 1) & (W_ - 1), cp = (c + 1) & (W_ - 1);
    int off[9] = { rm * W_ + cm, rm * W_ + c, rm * W_ + cp,
                   r  * W_ + cm, r  * W_ + c, r  * W_ + cp,
                   rp * W_ + cm, rp * W_ + c, rp * W_ + cp };

    const float* ab = alpha_new + (size_t)b * HW_;
    float mx = -1e30f, sm = 0.f;
    #pragma unroll
    for (int t = 0; t < 9; ++t) {
        float v = ab[off[t]];
        mx = fmaxf(mx, v);
        sm += v;
    }
    bool post = (mx > 0.1f) && ((sm * (1.0f / 9.0f)) < 0.2f);
    bool life = post && (pre_life[tid] > 0.5f);
    if (!life) {
        float* ob = out + (size_t)b * C_ * HW_ + pix;
        #pragma unroll
        for (int ch = 0; ch < C_; ++ch) ob[ch * HW_] = 0.f;
    }
}

extern "C" void kernel_launch(void* const* d_in, const int* in_sizes, int n_in,
                              void* d_out, int out_size, void* d_ws, size_t ws_size,
                              hipStream_t stream)
{
    const float* x     = (const float*)d_in[0];
    const float* rmask = (const float*)d_in[1];
    const float* filt  = (const float*)d_in[2];
    const float* W1    = (const float*)d_in[3];
    const float* b1    = (const float*)d_in[4];
    const float* W2    = (const float*)d_in[5];
    const float* b2    = (const float*)d_in[6];
    float* out = (float*)d_out;

    float* alpha_new = (float*)d_ws;                  // NPIX floats
    float* pre_life  = alpha_new + NPIX;              // NPIX floats
    _Float16* w1p    = (_Float16*)(pre_life + NPIX);  // 16384 f16 (32 KB)
    _Float16* w2p    = w1p + 32 * 512;                //  4096 f16 ( 8 KB)

    w_pack<<<dim3(80), dim3(256), 0, stream>>>(W1, W2, w1p, w2p);
    ca_step<<<dim3(NPIX / 256), dim3(256), 0, stream>>>(
        x, rmask, filt, w1p, b1, w2p, b2, out, alpha_new, pre_life);
    ca_mask<<<dim3(NPIX / 256), dim3(256), 0, stream>>>(alpha_new, pre_life, out);
}

// Round 11
// 93.651 us; speedup vs baseline: 4.4674x; 1.1715x over previous
//
#include <hip/hip_runtime.h>

#define B_   32
#define C_   16
#define H_   128
#define W_   128
#define HW_  (H_ * W_)
#define HID_ 128
#define FIN_ 64
#define NPIX (B_ * HW_)

typedef float    f32x4 __attribute__((ext_vector_type(4)));
typedef _Float16 f16x8 __attribute__((ext_vector_type(8)));

#define MFMA16(A, Bv, Cv) __builtin_amdgcn_mfma_f32_16x16x32_f16((A), (Bv), (Cv), 0, 0, 0)

// Slot->k convention (shared by ALL fragments; permutation-invariant since
// A and B use the same map):  k = 32*kc + 16*(j>>2) + 4*(lane>>4) + (j&3)
// w1p: 32 frags [(nt*2+kc)*2+s][lane][j], s=0 hi / s=1 lo; o = nt*16+(lane&15)
// w2p:  8 frags [kc2*2+s][lane][j];                       ch = lane&15
__global__ __launch_bounds__(256) void w_pack(
    const float* __restrict__ W1, const float* __restrict__ W2,
    _Float16* __restrict__ w1p, _Float16* __restrict__ w2p)
{
    int t = blockIdx.x * 256 + threadIdx.x;
    if (t < 32 * 512) {
        int frag = t >> 9, rem = t & 511, l = rem >> 3, j = rem & 7;
        int nt = frag >> 2, kc = (frag >> 1) & 1, s = frag & 1;
        int o = nt * 16 + (l & 15);
        int k = kc * 32 + 16 * (j >> 2) + 4 * (l >> 4) + (j & 3);
        float v = W1[o * FIN_ + k];
        _Float16 hi = (_Float16)v;
        _Float16 lo = (_Float16)(v - (float)hi);
        w1p[t] = s ? lo : hi;
    } else if (t < 32 * 512 + 8 * 512) {
        int u = t - 32 * 512;
        int frag = u >> 9, rem = u & 511, l = rem >> 3, j = rem & 7;
        int kc2 = frag >> 1, s = frag & 1;
        int ch = l & 15;
        int o = kc2 * 32 + 16 * (j >> 2) + 4 * (l >> 4) + (j & 3);
        float v = W2[ch * HID_ + o];
        _Float16 hi = (_Float16)v;
        _Float16 lo = (_Float16)(v - (float)hi);
        w2p[u] = s ? lo : hi;
    }
}

// Two 16-px tiles per wave through the whole body: doubles loads-in-flight in
// the conv, alternates the two tiles' MFMA chains (dependent-MFMA latency
// hidden), and halves LDS A-frag reads per MFMA. Per-tile math identical to
// the R10 kernel (same op order -> same results).
__global__ __launch_bounds__(256) void ca_step(
    const float* __restrict__ x,
    const float* __restrict__ rmask,
    const float* __restrict__ filt,
    const _Float16* __restrict__ w1p,
    const float* __restrict__ b1,
    const _Float16* __restrict__ w2p,
    const float* __restrict__ b2,
    float* __restrict__ out,
    float* __restrict__ alpha_new,
    float* __restrict__ pre_life)
{
    __shared__ uint4 sW1[32 * 64];   // 32 KB
    __shared__ uint4 sW2[8 * 64];    //  8 KB
    {
        const uint4* s1 = (const uint4*)w1p;
        for (int i = threadIdx.x; i < 32 * 64; i += 256) sW1[i] = s1[i];
        const uint4* s2 = (const uint4*)w2p;
        for (int i = threadIdx.x; i < 8 * 64; i += 256) sW2[i] = s2[i];
    }
    __syncthreads();

    int lane = threadIdx.x & 63, wv = threadIdx.x >> 6;
    int g = lane >> 4, li = lane & 15;
    const f16x8* w1f = (const f16x8*)sW1;
    const f16x8* w2f = (const f16x8*)sW2;

    #pragma unroll 1
    for (int it = 0; it < 2; ++it) {
        int tb = blockIdx.x * 16 + wv * 4 + it * 2;   // tile pair {tb, tb+1}

        int pxg[2], pixv[2];
        const float* xb_[2];
        int ro[2][3], co[2][3];
        #pragma unroll
        for (int s = 0; s < 2; ++s) {
            int pg = (tb + s) * 16 + li;
            pxg[s] = pg;
            int b = pg >> 14, pix = pg & (HW_ - 1);
            pixv[s] = pix;
            int rr = pix >> 7, cc = pix & (W_ - 1);
            int rm = (rr - 1) & (H_ - 1), rp = (rr + 1) & (H_ - 1);
            int cm = (cc - 1) & (W_ - 1), cp = (cc + 1) & (W_ - 1);
            ro[s][0] = rm * W_; ro[s][1] = rr * W_; ro[s][2] = rp * W_;
            co[s][0] = cm; co[s][1] = cc; co[s][2] = cp;
            xb_[s] = x + (size_t)b * C_ * HW_;
        }

        // conv: lane covers channels {g,g+4,g+8,g+12}; q=kc*2+s2 -> ch=8kc+4s2+g
        f16x8 yh[2][2], yl[2][2];   // [tile][kc]
        float pmax[2] = { -1e30f, -1e30f }, psum[2] = { 0.f, 0.f };
        #pragma unroll
        for (int q = 0; q < 4; ++q) {
            int ch = g + 4 * (q & 1) + 8 * (q >> 1);
            float n0[9], n1[9];
            const float* xc0 = xb_[0] + ch * HW_;
            const float* xc1 = xb_[1] + ch * HW_;
            #pragma unroll
            for (int u = 0; u < 9; ++u) n0[u] = xc0[ro[0][u / 3] + co[0][u % 3]];
            #pragma unroll
            for (int u = 0; u < 9; ++u) n1[u] = xc1[ro[1][u / 3] + co[1][u % 3]];
            #pragma unroll
            for (int f = 0; f < 4; ++f) {
                float a0 = 0.f, a1v = 0.f;
                #pragma unroll
                for (int u = 0; u < 9; ++u) {
                    float fw = filt[f * 9 + u];
                    a0  = fmaf(fw, n0[u], a0);
                    a1v = fmaf(fw, n1[u], a1v);
                }
                int kc = q >> 1, sl = (q & 1) * 4 + f;
                _Float16 h0 = (_Float16)a0;
                yh[0][kc][sl] = h0; yl[0][kc][sl] = (_Float16)(a0 - (float)h0);
                _Float16 h1 = (_Float16)a1v;
                yh[1][kc][sl] = h1; yl[1][kc][sl] = (_Float16)(a1v - (float)h1);
            }
            if (q == 0 && g == 3) {   // ch==3 alpha neighborhood
                #pragma unroll
                for (int u = 0; u < 9; ++u) {
                    pmax[0] = fmaxf(pmax[0], n0[u]); psum[0] += n0[u];
                    pmax[1] = fmaxf(pmax[1], n1[u]); psum[1] += n1[u];
                }
            }
        }
        if (g == 3) {
            #pragma unroll
            for (int s = 0; s < 2; ++s)
                pre_life[pxg[s]] = (pmax[s] > 0.1f && psum[s] * (1.f / 9.f) < 0.2f) ? 1.f : 0.f;
        }

        // prefetch epilogue operands (hidden under the GEMM section)
        float um[2], xold[2][4];
        #pragma unroll
        for (int s = 0; s < 2; ++s) {
            um[s] = (rmask[pxg[s]] <= 0.5f) ? 1.f : 0.f;
            #pragma unroll
            for (int t = 0; t < 4; ++t)
                xold[s][t] = xb_[s][(4 * g + t) * HW_ + pixv[s]];
        }

        // fused GEMM1 -> leaky/split -> GEMM2; both tiles alternate per MFMA
        f32x4 acc2[2] = { { 0.f, 0.f, 0.f, 0.f }, { 0.f, 0.f, 0.f, 0.f } };
        #pragma unroll
        for (int kc2 = 0; kc2 < 4; ++kc2) {
            f16x8 Hh[2], Hl[2];
            #pragma unroll
            for (int u = 0; u < 2; ++u) {
                int nt = kc2 * 2 + u;
                f32x4 a1[2] = { { 0.f, 0.f, 0.f, 0.f }, { 0.f, 0.f, 0.f, 0.f } };
                #pragma unroll
                for (int kc = 0; kc < 2; ++kc) {
                    int fb = (nt * 2 + kc) * 2;
                    f16x8 wh = w1f[(fb + 0) * 64 + lane];
                    f16x8 wl = w1f[(fb + 1) * 64 + lane];
                    a1[0] = MFMA16(wh, yh[0][kc], a1[0]);
                    a1[1] = MFMA16(wh, yh[1][kc], a1[1]);
                    a1[0] = MFMA16(wh, yl[0][kc], a1[0]);
                    a1[1] = MFMA16(wh, yl[1][kc], a1[1]);
                    a1[0] = MFMA16(wl, yh[0][kc], a1[0]);
                    a1[1] = MFMA16(wl, yh[1][kc], a1[1]);
                }
                #pragma unroll
                for (int t = 0; t < 4; ++t) {
                    float bb = b1[nt * 16 + 4 * g + t];
                    #pragma unroll
                    for (int s = 0; s < 2; ++s) {
                        float hv = a1[s][t] + bb;
                        float hpv = fmaxf(hv, 0.01f * hv);
                        _Float16 hi = (_Float16)hpv;
                        Hh[s][u * 4 + t] = hi;
                        Hl[s][u * 4 + t] = (_Float16)(hpv - (float)hi);
                    }
                }
            }
            f16x8 w2h = w2f[(kc2 * 2 + 0) * 64 + lane];
            f16x8 w2l = w2f[(kc2 * 2 + 1) * 64 + lane];
            acc2[0] = MFMA16(w2h, Hh[0], acc2[0]);
            acc2[1] = MFMA16(w2h, Hh[1], acc2[1]);
            acc2[0] = MFMA16(w2h, Hl[0], acc2[0]);
            acc2[1] = MFMA16(w2h, Hl[1], acc2[1]);
            acc2[0] = MFMA16(w2l, Hh[0], acc2[0]);
            acc2[1] = MFMA16(w2l, Hh[1], acc2[1]);
        }

        // epilogue: lane holds dx[ch=4g+t][px=li] for each tile
        #pragma unroll
        for (int s = 0; s < 2; ++s) {
            int b = pxg[s] >> 14;
            float aval = 0.f;
            #pragma unroll
            for (int t = 0; t < 4; ++t) {
                int ch = 4 * g + t;
                float ov = xold[s][t] + (acc2[s][t] + b2[ch]) * um[s];
                out[(size_t)b * C_ * HW_ + ch * HW_ + pixv[s]] = ov;
                if (t == 3) aval = ov;
            }
            if (g == 0) alpha_new[pxg[s]] = aval;   // g==0,t==3 -> ch 3
        }
    }
}

// Kernel B: post_life from new alpha plane; zero channels where !(pre & post).
__global__ __launch_bounds__(256) void ca_mask(
    const float* __restrict__ alpha_new,
    const float* __restrict__ pre_life,
    float* __restrict__ out)
{
    int tid = blockIdx.x * blockDim.x + threadIdx.x;
    if (tid >= NPIX) return;
    int b   = tid >> 14;
    int pix = tid & (HW_ - 1);
    int r   = pix >> 7;
    int c   = pix & (W_ - 1);

    int rm = (r - 1) & (H_ - 1), rp = (r + 1) & (H_ - 1);
    int cm = (c - 1) & (W_ - 1), cp = (c + 1) & (W_ - 1);
    int off[9] = { rm * W_ + cm, rm * W_ + c, rm * W_ + cp,
                   r  * W_ + cm, r  * W_ + c, r  * W_ + cp,
                   rp * W_ + cm, rp * W_ + c, rp * W_ + cp };

    const float* ab = alpha_new + (size_t)b * HW_;
    float mx = -1e30f, sm = 0.f;
    #pragma unroll
    for (int t = 0; t < 9; ++t) {
        float v = ab[off[t]];
        mx = fmaxf(mx, v);
        sm += v;
    }
    bool post = (mx > 0.1f) && ((sm * (1.0f / 9.0f)) < 0.2f);
    bool life = post && (pre_life[tid] > 0.5f);
    if (!life) {
        float* ob = out + (size_t)b * C_ * HW_ + pix;
        #pragma unroll
        for (int ch = 0; ch < C_; ++ch) ob[ch * HW_] = 0.f;
    }
}

extern "C" void kernel_launch(void* const* d_in, const int* in_sizes, int n_in,
                              void* d_out, int out_size, void* d_ws, size_t ws_size,
                              hipStream_t stream)
{
    const float* x     = (const float*)d_in[0];
    const float* rmask = (const float*)d_in[1];
    const float* filt  = (const float*)d_in[2];
    const float* W1    = (const float*)d_in[3];
    const float* b1    = (const float*)d_in[4];
    const float* W2    = (const float*)d_in[5];
    const float* b2    = (const float*)d_in[6];
    float* out = (float*)d_out;

    float* alpha_new = (float*)d_ws;                  // NPIX floats
    float* pre_life  = alpha_new + NPIX;              // NPIX floats
    _Float16* w1p    = (_Float16*)(pre_life + NPIX);  // 16384 f16 (32 KB)
    _Float16* w2p    = w1p + 32 * 512;                //  4096 f16 ( 8 KB)

    w_pack<<<dim3(80), dim3(256), 0, stream>>>(W1, W2, w1p, w2p);
    ca_step<<<dim3(NPIX / 256), dim3(256), 0, stream>>>(
        x, rmask, filt, w1p, b1, w2p, b2, out, alpha_new, pre_life);
    ca_mask<<<dim3(NPIX / 256), dim3(256), 0, stream>>>(alpha_new, pre_life, out);
}

// Round 12
// 92.480 us; speedup vs baseline: 4.5240x; 1.0127x over previous
//
#include <hip/hip_runtime.h>

#define B_   32
#define C_   16
#define H_   128
#define W_   128
#define HW_  (H_ * W_)
#define HID_ 128
#define FIN_ 64
#define NPIX (B_ * HW_)

#define XCH_ 532   // sX ch stride (floats): 4*532 % 32 == 16 -> g-groups 2-way alias (free)
#define XRW_ 132   // sX row stride (floats)

typedef float    f32x4 __attribute__((ext_vector_type(4)));
typedef _Float16 f16x8 __attribute__((ext_vector_type(8)));

#define MFMA16(A, Bv, Cv) __builtin_amdgcn_mfma_f32_16x16x32_f16((A), (Bv), (Cv), 0, 0, 0)

// Slot->k convention (shared by ALL fragments; permutation-invariant since
// A and B use the same map):  k = 32*kc + 16*(j>>2) + 4*(lane>>4) + (j&3)
// w1p: 32 frags [(nt*2+kc)*2+s][lane][j], s=0 hi / s=1 lo; o = nt*16+(lane&15)
// w2p:  8 frags [kc2*2+s][lane][j];                       ch = lane&15
__global__ __launch_bounds__(256) void w_pack(
    const float* __restrict__ W1, const float* __restrict__ W2,
    _Float16* __restrict__ w1p, _Float16* __restrict__ w2p)
{
    int t = blockIdx.x * 256 + threadIdx.x;
    if (t < 32 * 512) {
        int frag = t >> 9, rem = t & 511, l = rem >> 3, j = rem & 7;
        int nt = frag >> 2, kc = (frag >> 1) & 1, s = frag & 1;
        int o = nt * 16 + (l & 15);
        int k = kc * 32 + 16 * (j >> 2) + 4 * (l >> 4) + (j & 3);
        float v = W1[o * FIN_ + k];
        _Float16 hi = (_Float16)v;
        _Float16 lo = (_Float16)(v - (float)hi);
        w1p[t] = s ? lo : hi;
    } else if (t < 32 * 512 + 8 * 512) {
        int u = t - 32 * 512;
        int frag = u >> 9, rem = u & 511, l = rem >> 3, j = rem & 7;
        int kc2 = frag >> 1, s = frag & 1;
        int ch = l & 15;
        int o = kc2 * 32 + 16 * (j >> 2) + 4 * (l >> 4) + (j & 3);
        float v = W2[ch * HID_ + o];
        _Float16 hi = (_Float16)v;
        _Float16 lo = (_Float16)(v - (float)hi);
        w2p[u] = s ? lo : hi;
    }
}

// Each block = 2 full image rows (256 px) of one batch image. x neighborhood
// (4 rows x 16 ch, circularly wrapped) staged in LDS with coalesced float4
// loads; conv taps become low-latency conflict-free ds_reads. Weights in LDS
// as before. Per-tile math identical to R11 (same op order -> same bits).
__global__ __launch_bounds__(256) void ca_step(
    const float* __restrict__ x,
    const float* __restrict__ rmask,
    const float* __restrict__ filt,
    const _Float16* __restrict__ w1p,
    const float* __restrict__ b1,
    const _Float16* __restrict__ w2p,
    const float* __restrict__ b2,
    float* __restrict__ out,
    float* __restrict__ alpha_new,
    float* __restrict__ pre_life)
{
    __shared__ uint4 sW1[32 * 64];        // 32 KB
    __shared__ uint4 sW2[8 * 64];         //  8 KB
    __shared__ float sX[C_ * XCH_];       // ~34 KB: [ch][4 rows][128+pad]

    int b   = blockIdx.x >> 6;            // image
    int pix0 = (blockIdx.x & 63) * 256;   // first pixel of the 2-row strip
    int R0  = pix0 >> 7;                  // top row (even)

    {
        const uint4* s1 = (const uint4*)w1p;
        for (int i = threadIdx.x; i < 32 * 64; i += 256) sW1[i] = s1[i];
        const uint4* s2 = (const uint4*)w2p;
        for (int i = threadIdx.x; i < 8 * 64; i += 256) sW2[i] = s2[i];
        // stage x rows R0-1 .. R0+2, all 16 channels, coalesced float4
        const float4* xb4 = (const float4*)(x + (size_t)b * C_ * HW_);
        float4* sX4 = (float4*)sX;
        #pragma unroll
        for (int kk = 0; kk < 8; ++kk) {
            int i = threadIdx.x + kk * 256;   // 0..2047
            int ch = i >> 7, local = i & 127;
            int j = local >> 5, c4 = local & 31;
            int rowg = (R0 - 1 + j) & (H_ - 1);
            sX4[ch * (XCH_ / 4) + j * (XRW_ / 4) + c4] =
                xb4[ch * (HW_ / 4) + rowg * (W_ / 4) + c4];
        }
    }
    __syncthreads();

    int lane = threadIdx.x & 63, wv = threadIdx.x >> 6;
    int g = lane >> 4, li = lane & 15;
    const f16x8* w1f = (const f16x8*)sW1;
    const f16x8* w2f = (const f16x8*)sW2;

    #pragma unroll 1
    for (int it = 0; it < 2; ++it) {
        int pxg[2], pixv[2], rloc[2], cols[2][3];
        #pragma unroll
        for (int s = 0; s < 2; ++s) {
            int tt = wv * 4 + it * 2 + s;          // tile in block, 0..15
            int col = (tt & 7) * 16 + li;
            rloc[s] = tt >> 3;
            pixv[s] = pix0 + tt * 16 + li;
            pxg[s]  = b * HW_ + pixv[s];
            cols[s][0] = (col - 1) & (W_ - 1);
            cols[s][1] = col;
            cols[s][2] = (col + 1) & (W_ - 1);
        }

        // conv from LDS: lane covers channels {g,g+4,g+8,g+12}
        f16x8 yh[2][2], yl[2][2];
        float pmax[2] = { -1e30f, -1e30f }, psum[2] = { 0.f, 0.f };
        #pragma unroll
        for (int q = 0; q < 4; ++q) {
            int ch = g + 4 * (q & 1) + 8 * (q >> 1);
            const float* x0 = sX + ch * XCH_ + rloc[0] * XRW_;
            const float* x1 = sX + ch * XCH_ + rloc[1] * XRW_;
            float n0[9], n1[9];
            #pragma unroll
            for (int u = 0; u < 9; ++u) n0[u] = x0[(u / 3) * XRW_ + cols[0][u % 3]];
            #pragma unroll
            for (int u = 0; u < 9; ++u) n1[u] = x1[(u / 3) * XRW_ + cols[1][u % 3]];
            #pragma unroll
            for (int f = 0; f < 4; ++f) {
                float a0 = 0.f, a1v = 0.f;
                #pragma unroll
                for (int u = 0; u < 9; ++u) {
                    float fw = filt[f * 9 + u];
                    a0  = fmaf(fw, n0[u], a0);
                    a1v = fmaf(fw, n1[u], a1v);
                }
                int kc = q >> 1, sl = (q & 1) * 4 + f;
                _Float16 h0 = (_Float16)a0;
                yh[0][kc][sl] = h0; yl[0][kc][sl] = (_Float16)(a0 - (float)h0);
                _Float16 h1 = (_Float16)a1v;
                yh[1][kc][sl] = h1; yl[1][kc][sl] = (_Float16)(a1v - (float)h1);
            }
            if (q == 0 && g == 3) {   // ch==3 alpha neighborhood
                #pragma unroll
                for (int u = 0; u < 9; ++u) {
                    pmax[0] = fmaxf(pmax[0], n0[u]); psum[0] += n0[u];
                    pmax[1] = fmaxf(pmax[1], n1[u]); psum[1] += n1[u];
                }
            }
        }
        if (g == 3) {
            #pragma unroll
            for (int s = 0; s < 2; ++s)
                pre_life[pxg[s]] = (pmax[s] > 0.1f && psum[s] * (1.f / 9.f) < 0.2f) ? 1.f : 0.f;
        }

        // epilogue operands: rmask global (coalesced), x-centers from LDS
        float um[2], xold[2][4];
        #pragma unroll
        for (int s = 0; s < 2; ++s) {
            um[s] = (rmask[pxg[s]] <= 0.5f) ? 1.f : 0.f;
            #pragma unroll
            for (int t = 0; t < 4; ++t)
                xold[s][t] = sX[(4 * g + t) * XCH_ + (rloc[s] + 1) * XRW_ + cols[s][1]];
        }

        // fused GEMM1 -> leaky/split -> GEMM2; both tiles alternate per MFMA
        f32x4 acc2[2] = { { 0.f, 0.f, 0.f, 0.f }, { 0.f, 0.f, 0.f, 0.f } };
        #pragma unroll
        for (int kc2 = 0; kc2 < 4; ++kc2) {
            f16x8 Hh[2], Hl[2];
            #pragma unroll
            for (int u = 0; u < 2; ++u) {
                int nt = kc2 * 2 + u;
                f32x4 a1[2] = { { 0.f, 0.f, 0.f, 0.f }, { 0.f, 0.f, 0.f, 0.f } };
                #pragma unroll
                for (int kc = 0; kc < 2; ++kc) {
                    int fb = (nt * 2 + kc) * 2;
                    f16x8 wh = w1f[(fb + 0) * 64 + lane];
                    f16x8 wl = w1f[(fb + 1) * 64 + lane];
                    a1[0] = MFMA16(wh, yh[0][kc], a1[0]);
                    a1[1] = MFMA16(wh, yh[1][kc], a1[1]);
                    a1[0] = MFMA16(wh, yl[0][kc], a1[0]);
                    a1[1] = MFMA16(wh, yl[1][kc], a1[1]);
                    a1[0] = MFMA16(wl, yh[0][kc], a1[0]);
                    a1[1] = MFMA16(wl, yh[1][kc], a1[1]);
                }
                #pragma unroll
                for (int t = 0; t < 4; ++t) {
                    float bb = b1[nt * 16 + 4 * g + t];
                    #pragma unroll
                    for (int s = 0; s < 2; ++s) {
                        float hv = a1[s][t] + bb;
                        float hpv = fmaxf(hv, 0.01f * hv);
                        _Float16 hi = (_Float16)hpv;
                        Hh[s][u * 4 + t] = hi;
                        Hl[s][u * 4 + t] = (_Float16)(hpv - (float)hi);
                    }
                }
            }
            f16x8 w2h = w2f[(kc2 * 2 + 0) * 64 + lane];
            f16x8 w2l = w2f[(kc2 * 2 + 1) * 64 + lane];
            acc2[0] = MFMA16(w2h, Hh[0], acc2[0]);
            acc2[1] = MFMA16(w2h, Hh[1], acc2[1]);
            acc2[0] = MFMA16(w2h, Hl[0], acc2[0]);
            acc2[1] = MFMA16(w2h, Hl[1], acc2[1]);
            acc2[0] = MFMA16(w2l, Hh[0], acc2[0]);
            acc2[1] = MFMA16(w2l, Hh[1], acc2[1]);
        }

        // epilogue: lane holds dx[ch=4g+t][px=li] for each tile
        #pragma unroll
        for (int s = 0; s < 2; ++s) {
            float aval = 0.f;
            #pragma unroll
            for (int t = 0; t < 4; ++t) {
                int ch = 4 * g + t;
                float ov = xold[s][t] + (acc2[s][t] + b2[ch]) * um[s];
                out[(size_t)b * C_ * HW_ + ch * HW_ + pixv[s]] = ov;
                if (t == 3) aval = ov;
            }
            if (g == 0) alpha_new[pxg[s]] = aval;   // g==0,t==3 -> ch 3
        }
    }
}

// Kernel B: post_life from new alpha plane; zero channels where !(pre & post).
__global__ __launch_bounds__(256) void ca_mask(
    const float* __restrict__ alpha_new,
    const float* __restrict__ pre_life,
    float* __restrict__ out)
{
    int tid = blockIdx.x * blockDim.x + threadIdx.x;
    if (tid >= NPIX) return;
    int b   = tid >> 14;
    int pix = tid & (HW_ - 1);
    int r   = pix >> 7;
    int c   = pix & (W_ - 1);

    int rm = (r - 1) & (H_ - 1), rp = (r + 1) & (H_ - 1);
    int cm = (c - 1) & (W_ - 1), cp = (c + 1) & (W_ - 1);
    int off[9] = { rm * W_ + cm, rm * W_ + c, rm * W_ + cp,
                   r  * W_ + cm, r  * W_ + c, r  * W_ + cp,
                   rp * W_ + cm, rp * W_ + c, rp * W_ + cp };

    const float* ab = alpha_new + (size_t)b * HW_;
    float mx = -1e30f, sm = 0.f;
    #pragma unroll
    for (int t = 0; t < 9; ++t) {
        float v = ab[off[t]];
        mx = fmaxf(mx, v);
        sm += v;
    }
    bool post = (mx > 0.1f) && ((sm * (1.0f / 9.0f)) < 0.2f);
    bool life = post && (pre_life[tid] > 0.5f);
    if (!life) {
        float* ob = out + (size_t)b * C_ * HW_ + pix;
        #pragma unroll
        for (int ch = 0; ch < C_; ++ch) ob[ch * HW_] = 0.f;
    }
}

extern "C" void kernel_launch(void* const* d_in, const int* in_sizes, int n_in,
                              void* d_out, int out_size, void* d_ws, size_t ws_size,
                              hipStream_t stream)
{
    const float* x     = (const float*)d_in[0];
    const float* rmask = (const float*)d_in[1];
    const float* filt  = (const float*)d_in[2];
    const float* W1    = (const float*)d_in[3];
    const float* b1    = (const float*)d_in[4];
    const float* W2    = (const float*)d_in[5];
    const float* b2    = (const float*)d_in[6];
    float* out = (float*)d_out;

    float* alpha_new = (float*)d_ws;                  // NPIX floats
    float* pre_life  = alpha_new + NPIX;              // NPIX floats
    _Float16* w1p    = (_Float16*)(pre_life + NPIX);  // 16384 f16 (32 KB)
    _Float16* w2p    = w1p + 32 * 512;                //  4096 f16 ( 8 KB)

    w_pack<<<dim3(80), dim3(256), 0, stream>>>(W1, W2, w1p, w2p);
    ca_step<<<dim3(NPIX / 256), dim3(256), 0, stream>>>(
        x, rmask, filt, w1p, b1, w2p, b2, out, alpha_new, pre_life);
    ca_mask<<<dim3(NPIX / 256), dim3(256), 0, stream>>>(alpha_new, pre_life, out);
}